// Round 11
// baseline (290.435 us; speedup 1.0000x reference)
//
#include <hip/hip_runtime.h>

#define DD 256
#define KK 8192
#define HW 1024
#define NROWS 16384
#define NELEM 4194304
#define MT 32            // rerank row-tile (loss-order preserving: DO NOT CHANGE)
#define MS 64            // screen row-tile
#define WCAP 1024
#define NSLICE 4
#define SZ 15.875f                   // z scale: 127/8
#define SE 1040384.f                 // code scale: 127*8192 (no clamp active)
#define C2SCR (-2.f / 16516096.f)    // -2/(SZ*SE)  [r5-verified]
#define EMAX 1.220703125e-4f         // 1/8192 exact: |e_i| <= EMAX
#define DLTE (0.5f / 1040384.f)      // code quant err: <= 0.5/SE

typedef __attribute__((ext_vector_type(4))) float f32x4;
typedef __attribute__((ext_vector_type(4))) int i32x4;
typedef unsigned short ushort;
typedef unsigned int uint;
typedef unsigned long long u64;

// ---- exact replication of numpy pairwise_sum (n=256) over squares ----
__device__ __forceinline__ float np_pw128_sq(const float* p) {
  float r[8];
#pragma unroll
  for (int j = 0; j < 8; ++j) r[j] = __fmul_rn(p[j], p[j]);
  for (int i = 8; i < 128; i += 8) {
#pragma unroll
    for (int j = 0; j < 8; ++j)
      r[j] = __fadd_rn(r[j], __fmul_rn(p[i + j], p[i + j]));
  }
  return __fadd_rn(__fadd_rn(__fadd_rn(r[0], r[1]), __fadd_rn(r[2], r[3])),
                   __fadd_rn(__fadd_rn(r[4], r[5]), __fadd_rn(r[6], r[7])));
}

// order-preserving float<->uint (screened minima are NEGATIVE - r5 lesson)
__device__ __forceinline__ uint fenc(float f) {
  uint u = __float_as_uint(f);
  return (u & 0x80000000u) ? ~u : (u | 0x80000000u);
}
__device__ __forceinline__ float fdec(uint k) {
  return __uint_as_float((k & 0x80000000u) ? (k & 0x7FFFFFFFu) : ~k);
}

__device__ __forceinline__ int q8(float v, float s) {
  return min(127, max(-127, __float2int_rn(v * s)));
}

// running top-2 (min, argmin-local, min2); i8-acc version (r5-verified math)
struct Top2 { float m1, m2; int i1; };

__device__ __forceinline__ void top2i(Top2& s, const i32x4 a, const f32x4 Bs,
                                      int ibase) {
  float d0 = fmaf(C2SCR, (float)a[0], Bs[0]);
  float d1 = fmaf(C2SCR, (float)a[1], Bs[1]);
  float d2 = fmaf(C2SCR, (float)a[2], Bs[2]);
  float d3 = fmaf(C2SCR, (float)a[3], Bs[3]);
  float lo01 = fminf(d0, d1), hi01 = fmaxf(d0, d1);
  int io01 = d1 < d0 ? ibase + 1 : ibase;
  float lo23 = fminf(d2, d3), hi23 = fmaxf(d2, d3);
  int io23 = d3 < d2 ? ibase + 3 : ibase + 2;
  float n1 = fminf(lo01, lo23);
  int ni = lo23 < lo01 ? io23 : io01;
  float n2 = fminf(fmaxf(lo01, lo23), fminf(hi01, hi23));
  s.m2 = fminf(fmaxf(s.m1, n1), fminf(s.m2, n2));   // uses OLD m1
  s.i1 = n1 < s.m1 ? ni : s.i1;
  s.m1 = fminf(s.m1, n1);
}

__device__ __forceinline__ uint pack_m2(float m2, int i1) {
  // bf16 rounded toward -inf (conservative), 5-bit local idx in low bits
  uint u = __float_as_uint(m2);
  uint hi = u & 0xFFFF0000u;
  if ((u & 0x80000000u) && (u & 0xFFFFu)) hi += 0x10000u;
  return hi | (uint)i1;
}

// ======== prep: Bk + inits | cbI i8 fragments (r5-verified layout) ========
__global__ __launch_bounds__(256) void vq_prep(const float* __restrict__ cb,
                                               float* __restrict__ Bk,
                                               i32x4* __restrict__ cbI,
                                               uint* __restrict__ rowMinG,
                                               int* __restrict__ hist,
                                               float* __restrict__ loss) {
  const int b = blockIdx.x, t = threadIdx.x;
  if (b < 64) {                // ||e_k||^2, numpy-exact: half per thread
    int tid2 = b * 256 + t;
    int k = tid2 >> 1, half = tid2 & 1;
    float h = np_pw128_sq(cb + (size_t)k * DD + half * 128);
    float ho = __shfl_xor(h, 1);          // partner half (adjacent lane)
    if (half == 0) Bk[k] = __fadd_rn(h, ho);   // np(p) + np(p+128), order kept
    rowMinG[tid2] = 0xFFFFFFFFu;          // 16384 entries, exactly covered
    if (b < 32) hist[tid2] = 0;           // 8192 entries
    if (tid2 == 0) loss[0] = 0.f;
  } else {                     // i8 fragments: elem j of int4 (g*4+s, lane) is
    // dim d = s*64 + (lane>>4)*16 + j of code g*16 + (lane&15)  [r5-verified]
    int tid = (b - 64) * 256 + t;          // 131072 threads
    int g = tid >> 8, s = (tid >> 6) & 3, lane = tid & 63;
    int code = g * 16 + (lane & 15);
    int d0 = s * 64 + (lane >> 4) * 16;
    const float* p = cb + (size_t)code * DD + d0;
    int v[16];
#pragma unroll
    for (int j = 0; j < 16; ++j) v[j] = q8(p[j], SE);
    i32x4 pk;
    pk.x = (v[0] & 255) | ((v[1] & 255) << 8) | ((v[2] & 255) << 16) | (v[3] << 24);
    pk.y = (v[4] & 255) | ((v[5] & 255) << 8) | ((v[6] & 255) << 16) | (v[7] << 24);
    pk.z = (v[8] & 255) | ((v[9] & 255) << 8) | ((v[10] & 255) << 16) | (v[11] << 24);
    pk.w = (v[12] & 255) | ((v[13] & 255) << 8) | ((v[14] & 255) << 16) | (v[15] << 24);
    cbI[(size_t)(g * 4 + s) * 64 + lane] = pk;
  }
}

// ======== screen: i8 MFMA K=64, 64 rows/block, shuffle-free subset top2 ====
// vs r10 bf16 screen: codebook bytes /2, MFMA instrs /2, aF regs /2 (64 -> fits
// the 128-VGPR reality), and the per-tile butterfly (384 shfl + ~800 VALU per
// wave) is GONE: each (lane,quad) tracks top2 over its own strided 32-code
// subset; stores are coalesced, no cross-lane until one rmin merge at the end.
// Subset = 8 gg; entry e = sti*4+quad in [0,256) -> tA/tB sizes unchanged.
__global__ __launch_bounds__(256) void vq_screen(
    const float* __restrict__ z, const i32x4* __restrict__ cbI,
    const float* __restrict__ Bk, float* __restrict__ tA,
    uint* __restrict__ tB, uint* __restrict__ rowMinG) {
  __shared__ signed char ztI[MS][272];   // 17.4 KB; rows 16B-aligned
  __shared__ float BkS[2048];            // this block's code-slice norms
  const int bid = blockIdx.x;
  const int rt = bid >> 2, cs = bid & 3;
  const int t = threadIdx.x;
  const int n0 = rt * MS;
  const int bimg = n0 >> 10, hw0 = n0 & 1023;
  const float* zb = z + (size_t)bimg * DD * HW + hw0;

  for (int li = t; li < 64 * 64; li += 256) {   // d = li>>4, r4 = (li&15)*4
    int d = li >> 4, r4 = (li & 15) * 4;
    float4 v = *(const float4*)(zb + (size_t)d * HW + r4);
    ztI[r4 + 0][d] = (signed char)q8(v.x, SZ);
    ztI[r4 + 1][d] = (signed char)q8(v.y, SZ);
    ztI[r4 + 2][d] = (signed char)q8(v.z, SZ);
    ztI[r4 + 3][d] = (signed char)q8(v.w, SZ);
  }
  for (int li = t; li < 2048; li += 256) BkS[li] = Bk[cs * 2048 + li];
  __syncthreads();

  const int w = t >> 6, lane = t & 63;
  const int quad = lane >> 4, n16 = lane & 15;

  i32x4 aF0[4], aF1[4], aF2[4], aF3[4];   // z fragments, 4 row-groups (64 VGPR)
#pragma unroll
  for (int s = 0; s < 4; ++s) {
    aF0[s] = *(const i32x4*)&ztI[n16][s * 64 + quad * 16];
    aF1[s] = *(const i32x4*)&ztI[16 + n16][s * 64 + quad * 16];
    aF2[s] = *(const i32x4*)&ztI[32 + n16][s * 64 + quad * 16];
    aF3[s] = *(const i32x4*)&ztI[48 + n16][s * 64 + quad * 16];
  }

  const int gg0 = cs * 128 + w * 32;   // wave owns 32 gg = 4 subsets of 8
  const int cbase = cs * 2048;
  Top2 c0 = {3.4e38f, 3.4e38f, 0}, c1 = {3.4e38f, 3.4e38f, 0};
  Top2 c2 = {3.4e38f, 3.4e38f, 0}, c3 = {3.4e38f, 3.4e38f, 0};
  float r0m = 3.4e38f, r1m = 3.4e38f, r2m = 3.4e38f, r3m = 3.4e38f;

  for (int gp = 0; gp < 32; ++gp) {
    const int gg = gg0 + gp;
    i32x4 bc[4];
#pragma unroll
    for (int s = 0; s < 4; ++s) bc[s] = cbI[(size_t)gg * 256 + s * 64 + lane];
    i32x4 A0 = {0,0,0,0}, A1 = {0,0,0,0}, A2 = {0,0,0,0}, A3 = {0,0,0,0};
#pragma unroll
    for (int s = 0; s < 4; ++s) {
      A0 = __builtin_amdgcn_mfma_i32_16x16x64_i8(bc[s], aF0[s], A0, 0, 0, 0);
      A1 = __builtin_amdgcn_mfma_i32_16x16x64_i8(bc[s], aF1[s], A1, 0, 0, 0);
      A2 = __builtin_amdgcn_mfma_i32_16x16x64_i8(bc[s], aF2[s], A2, 0, 0, 0);
      A3 = __builtin_amdgcn_mfma_i32_16x16x64_i8(bc[s], aF3[s], A3, 0, 0, 0);
    }
    const f32x4 Bs = *(const f32x4*)(BkS + gg * 16 - cbase + quad * 4);
    const int ib = (gp & 7) * 4;        // local idx = ggl*4 + reg (5 bits)
    top2i(c0, A0, Bs, ib); top2i(c1, A1, Bs, ib);
    top2i(c2, A2, Bs, ib); top2i(c3, A3, Bs, ib);

    if ((gp & 7) == 7) {   // subset complete: coalesced store, no shuffles
      const int sti = (gg - 7) >> 3;
      const size_t tbase = (size_t)(sti * 4 + quad) * NROWS + n0;
      __builtin_nontemporal_store(c0.m1, &tA[tbase + n16]);
      __builtin_nontemporal_store(pack_m2(c0.m2, c0.i1), &tB[tbase + n16]);
      __builtin_nontemporal_store(c1.m1, &tA[tbase + 16 + n16]);
      __builtin_nontemporal_store(pack_m2(c1.m2, c1.i1), &tB[tbase + 16 + n16]);
      __builtin_nontemporal_store(c2.m1, &tA[tbase + 32 + n16]);
      __builtin_nontemporal_store(pack_m2(c2.m2, c2.i1), &tB[tbase + 32 + n16]);
      __builtin_nontemporal_store(c3.m1, &tA[tbase + 48 + n16]);
      __builtin_nontemporal_store(pack_m2(c3.m2, c3.i1), &tB[tbase + 48 + n16]);
      r0m = fminf(r0m, c0.m1); r1m = fminf(r1m, c1.m1);
      r2m = fminf(r2m, c2.m1); r3m = fminf(r3m, c3.m1);
      c0 = Top2{3.4e38f, 3.4e38f, 0}; c1 = Top2{3.4e38f, 3.4e38f, 0};
      c2 = Top2{3.4e38f, 3.4e38f, 0}; c3 = Top2{3.4e38f, 3.4e38f, 0};
    }
  }
  // merge rmin across the 4 quads (lane bits 4-5), then one atomic per row
#pragma unroll
  for (int off = 16; off <= 32; off <<= 1) {
    r0m = fminf(r0m, __shfl_xor(r0m, off));
    r1m = fminf(r1m, __shfl_xor(r1m, off));
    r2m = fminf(r2m, __shfl_xor(r2m, off));
    r3m = fminf(r3m, __shfl_xor(r3m, off));
  }
  if (quad == 0) {
    atomicMin(&rowMinG[n0 + n16], fenc(r0m));
    atomicMin(&rowMinG[n0 + 16 + n16], fenc(r1m));
    atomicMin(&rowMinG[n0 + 32 + n16], fenc(r2m));
    atomicMin(&rowMinG[n0 + 48 + n16], fenc(r3m));
  }
}

// ======== rerank: per-row exact margin | candidates | exact | epilogue =====
// thr[r] = screened_rowmin + 2*err_row*1.0625 + 1e-5, where err_row is the
// EXACT deterministic bound (1/8192)*sum|z-zhat/sz| + (0.5/SE)*||z||_1
// computed from the staged row (triangle inequality; clamped rows auto-widen).
// Exact path + loss/epilogue byte-identical to r7-r10 -> bit-exact outputs.
__global__ __launch_bounds__(256) void vq_rerank(
    const float* __restrict__ z, const float* __restrict__ cb,
    const float* __restrict__ Bk, const float* __restrict__ tA,
    const uint* __restrict__ tB, const uint* __restrict__ rowMinG,
    float* __restrict__ out, int* __restrict__ hist,
    float* __restrict__ loss_acc) {
  __shared__ float zt[MT][DD + 1];
  __shared__ float ArS[MT];
  __shared__ float thrS[MT];
  __shared__ int wl[WCAP];
  __shared__ int wcnt;
  __shared__ int ovf;
  __shared__ u64 rowBestS[MT];
  __shared__ int kwin[MT];
  __shared__ float lred[4];

  const int t = threadIdx.x;
  const int n0 = blockIdx.x * MT;
  const int bimg = n0 >> 10, hw0 = n0 & 1023;
  const float* zb = z + (size_t)bimg * DD * HW + hw0;

  if (t == 0) { wcnt = 0; ovf = 0; }
  if (t < MT) rowBestS[t] = 0xFFFFFFFFFFFFFFFFull;
  for (int li = t; li < MT * DD; li += 256) {
    int d = li >> 5, r = li & 31;
    zt[r][d] = zb[d * HW + r];
  }
  __syncthreads();

  const int w = t >> 6, lane = t & 63;

  if (t >= 128 && t < 192) {   // wave 2: Arow (numpy-exact) + exact margin
    int rr = (t - 128) >> 1, half = t & 1;
    const float* zp = &zt[rr][half * 128];
    float h = np_pw128_sq(zp);
    float dsum = 0.f, asum = 0.f;
    for (int i = 0; i < 128; ++i) {
      float v = zp[i];
      float zq = (float)q8(v, SZ) * (1.f / SZ);   // replicate screen quant
      dsum += fabsf(v - zq);
      asum += fabsf(v);
    }
    float ho = __shfl_xor(h, 1);
    float dso = __shfl_xor(dsum, 1);
    float aso = __shfl_xor(asum, 1);
    if (half == 0) {
      ArS[rr] = __fadd_rn(h, ho);        // h[0] + h[1], order kept
      float err = EMAX * (dsum + dso) + DLTE * (asum + aso);
      thrS[rr] = fdec(rowMinG[n0 + rr]) + 2.f * err * 1.0625f + 1e-5f;
    }
  }
  __syncthreads();

  auto exact_one = [&](int rr, int code) {   // numpy-exact ascending-d chain
    const float* cp = cb + (size_t)code * DD;
    float dot = 0.f;
#pragma unroll
    for (int d0 = 0; d0 < DD; d0 += 4) {
      float4 v = *(const float4*)(cp + d0);
      dot = fmaf(zt[rr][d0 + 0], v.x, dot);
      dot = fmaf(zt[rr][d0 + 1], v.y, dot);
      dot = fmaf(zt[rr][d0 + 2], v.z, dot);
      dot = fmaf(zt[rr][d0 + 3], v.w, dot);
    }
    float bd = __fsub_rn(__fadd_rn(ArS[rr], Bk[code]), __fmul_rn(2.f, dot));
    atomicMin(&rowBestS[rr], ((u64)__float_as_uint(bd) << 32) | (unsigned)code);
  };

  // candidate scan: entry q = sti*4+quad covers 32 strided codes
  // code = sti*128 + ggl*16 + quad*4 + reg  (ggl = local>>2, reg = local&3)
  const int r4 = (t & 7) << 2;
  float th[4];
#pragma unroll
  for (int e2 = 0; e2 < 4; ++e2) th[e2] = thrS[r4 + e2];

  for (int it = 0; it < 8; ++it) {
    const int li = it * 256 + t;          // 0..2047
    const int q = li >> 3;
    const int sti = q >> 2, quad = q & 3;
    const f32x4 a4 = __builtin_nontemporal_load(
        (const f32x4*)&tA[(size_t)q * NROWS + n0 + r4]);
#pragma unroll
    for (int e2 = 0; e2 < 4; ++e2) {
      if (a4[e2] <= th[e2]) {
        const int rr = r4 + e2;
        const uint pk = __builtin_nontemporal_load(
            &tB[(size_t)q * NROWS + n0 + rr]);
        const float m2f = __uint_as_float(pk & 0xFFFF0000u);
        const int cbase2 = sti * 128 + quad * 4;
        if (m2f <= th[e2]) {           // rare near-tie -> full 32-code subset
          for (int c = 0; c < 32; ++c) {
            int code = cbase2 + (c >> 2) * 16 + (c & 3);
            int pos = atomicAdd(&wcnt, 1);
            if (pos < WCAP) wl[pos] = (rr << 16) | code;
            else ovf = 1;
          }
        } else {
          int local = (int)(pk & 31u);
          int code = cbase2 + (local >> 2) * 16 + (local & 3);
          int pos = atomicAdd(&wcnt, 1);
          if (pos < WCAP) wl[pos] = (rr << 16) | code;
          else ovf = 1;
        }
      }
    }
  }
  __syncthreads();

  const int cnt = min(wcnt, WCAP);
  for (int e = t; e < cnt; e += 256) {
    const int ent = wl[e];
    exact_one(ent >> 16, ent & 0xFFFF);
  }
  if (ovf) {   // never in practice: idempotent full re-scan (atomicMin union)
    for (int it = 0; it < 8; ++it) {
      const int li = it * 256 + t;
      const int q = li >> 3;
      const int sti = q >> 2, quad = q & 3;
      const f32x4 a4 = *(const f32x4*)&tA[(size_t)q * NROWS + n0 + r4];
#pragma unroll
      for (int e2 = 0; e2 < 4; ++e2) {
        if (a4[e2] <= th[e2]) {
          const int rr = r4 + e2;
          const uint pk = tB[(size_t)q * NROWS + n0 + rr];
          const float m2f = __uint_as_float(pk & 0xFFFF0000u);
          const int cbase2 = sti * 128 + quad * 4;
          if (m2f <= th[e2]) {
            for (int c = 0; c < 32; ++c)
              exact_one(rr, cbase2 + (c >> 2) * 16 + (c & 3));
          } else {
            int local = (int)(pk & 31u);
            exact_one(rr, cbase2 + (local >> 2) * 16 + (local & 3));
          }
        }
      }
    }
  }
  __syncthreads();

  // ---- epilogue: indices + hist + z_q_st + loss (zt resident) ----
  if (t < MT) {
    int bi = (int)(rowBestS[t] & 0xFFFFFFFFull);
    kwin[t] = bi;
    atomicAdd(&hist[bi], 1);
    out[(size_t)NELEM + 1 + n0 + t] = (float)bi;
  }
  __syncthreads();

  float lsum = 0.f;
  for (int it = 0; it < MT * DD / 256; ++it) {
    int li = it * 256 + t;
    int d = li >> 5, rr = li & 31;
    float ze = zt[rr][d];
    float zq = cb[(size_t)kwin[rr] * DD + d];
    float diff = __fsub_rn(zq, ze);
    float st = __fadd_rn(ze, diff);        // z_e + (z_q - z_e)
    out[(size_t)(bimg * DD + d) * HW + hw0 + rr] = st;
    lsum = fmaf(diff, diff, lsum);
  }
#pragma unroll
  for (int off = 32; off > 0; off >>= 1) lsum += __shfl_down(lsum, off);
  if (lane == 0) lred[w] = lsum;
  __syncthreads();
  if (t == 0)
    atomicAdd(loss_acc, ((lred[0] + lred[1]) + (lred[2] + lred[3])));
}

// ---------------- finalize: vq_loss + perplexity ----------------
__global__ __launch_bounds__(256) void vq_final(const int* __restrict__ hist,
                                                const float* __restrict__ loss,
                                                float* __restrict__ out) {
  __shared__ float sred[256];
  int t = threadIdx.x;
  float s = 0.f;
  for (int k = t; k < KK; k += 256) {
    float p = (float)hist[k] * (1.f / 16384.f);
    s += p * logf(p + 1e-10f);
  }
  sred[t] = s;
  __syncthreads();
  for (int off = 128; off > 0; off >>= 1) {
    if (t < off) sred[t] += sred[t + off];
    __syncthreads();
  }
  if (t == 0) {
    float L = loss[0] / (float)NELEM;
    out[NELEM] = 1.25f * L;
    out[(size_t)NELEM + 1 + NROWS] = expf(-sred[0]);
  }
}

extern "C" void kernel_launch(void* const* d_in, const int* in_sizes, int n_in,
                              void* d_out, int out_size, void* d_ws, size_t ws_size,
                              hipStream_t stream) {
  const float* z = (const float*)d_in[0];   // (16,256,32,32) fp32
  const float* cb = (const float*)d_in[1];  // (8192,256) fp32
  float* out = (float*)d_out;               // fp32: [z_q_st | loss | idx | perp]

  float* wsf = (float*)d_ws;
  int* hist = (int*)d_ws;                          // 8192 ints
  float* loss = wsf + 8192;                        // 1 (+pad)
  float* Bk = wsf + 8448;                          // 8192
  uint* rowMinG = (uint*)(wsf + 16640);            // 16384 u32
  i32x4* cbI = (i32x4*)(wsf + 33024);              // 2 MB i8 fragments
  float* tA = wsf + 557312;                        // 256*16384 f32 (16.8 MB)
  uint* tB = (uint*)(wsf + 4751616);               // 256*16384 u32 (16.8 MB)

  // no memset nodes: prep initializes hist/loss/rowMinG
  vq_prep<<<576, 256, 0, stream>>>(cb, Bk, cbI, rowMinG, hist, loss);
  vq_screen<<<(NROWS / MS) * NSLICE, 256, 0, stream>>>(z, cbI, Bk, tA, tB,
                                                       rowMinG);
  vq_rerank<<<NROWS / MT, 256, 0, stream>>>(z, cb, Bk, tA, tB, rowMinG, out,
                                            hist, loss);
  vq_final<<<1, 256, 0, stream>>>(hist, loss, out);
}